// Round 16
// baseline (141.763 us; speedup 1.0000x reference)
//
#include <hip/hip_runtime.h>
#include <hip/hip_bf16.h>

// Problem constants (B=1)
#define T_DIM 4096
#define E_DIM 1024
#define H_DIM 16
#define HD_DIM 64
#define LOG2E_F 1.4426950408889634f
#define QSCALE_F (0.125f * LOG2E_F)   // SCALE * log2(e), folded into Qp

typedef __bf16 bf16_t;
typedef __bf16 bf16x8 __attribute__((ext_vector_type(8)));
typedef __bf16 bf16x4 __attribute__((ext_vector_type(4)));
typedef float  f32x4  __attribute__((ext_vector_type(4)));

// ---- helpers ----
__device__ inline void stage8(bf16_t* dst, const float* src) {
  const f32x4* s4 = (const f32x4*)src;
  f32x4 a = s4[0], b = s4[1];
  bf16x8 o;
  o[0] = (bf16_t)a[0]; o[1] = (bf16_t)a[1]; o[2] = (bf16_t)a[2]; o[3] = (bf16_t)a[3];
  o[4] = (bf16_t)b[0]; o[5] = (bf16_t)b[1]; o[6] = (bf16_t)b[2]; o[7] = (bf16_t)b[3];
  *(bf16x8*)dst = o;
}
__device__ inline void stage8(bf16_t* dst, const bf16_t* src) {
  *(bf16x8*)dst = *(const bf16x8*)src;
}

__device__ inline void gld_lds16(const bf16_t* g, bf16_t* l) {
  __builtin_amdgcn_global_load_lds(
      (const __attribute__((address_space(1))) unsigned int*)g,
      (__attribute__((address_space(3))) unsigned int*)l, 16, 0, 0);
}

__device__ inline float fexp2(float x) {  // raw v_exp_f32 (exp2)
  float r;
  asm("v_exp_f32 %0, %1" : "=v"(r) : "v"(x));
  return r;
}

// raw barrier (no implicit vmcnt(0) drain) + compiler memory fence
__device__ inline void block_sync() {
  asm volatile("" ::: "memory");
  __builtin_amdgcn_s_barrier();
  asm volatile("" ::: "memory");
}

// ---- fp32 -> bf16 conversion for all 7 inputs (one launch) ----
__global__ __launch_bounds__(256) void cvt_all(
    const float* __restrict__ q, const float* __restrict__ k, const float* __restrict__ v,
    const float* __restrict__ Wq, const float* __restrict__ Wk,
    const float* __restrict__ Wv, const float* __restrict__ Wo,
    bf16_t* qb, bf16_t* kb, bf16_t* vb,
    bf16_t* Wqb, bf16_t* Wkb, bf16_t* Wvb, bf16_t* Wob) {
  for (int u = blockIdx.x * 256 + threadIdx.x; u < 2097152; u += gridDim.x * 256) {
    const float* s; bf16_t* d; int i;
    if (u < 1572864) {
      int seg = u >> 19, off = u & 524287;
      s = seg == 0 ? q : (seg == 1 ? k : v);
      d = seg == 0 ? qb : (seg == 1 ? kb : vb);
      i = off;
    } else {
      int w = u - 1572864;
      int seg = w >> 17, off = w & 131071;
      s = seg == 0 ? Wq : seg == 1 ? Wk : seg == 2 ? Wv : Wo;
      d = seg == 0 ? Wqb : seg == 1 ? Wkb : seg == 2 ? Wvb : Wob;
      i = off;
    }
    stage8(d + (size_t)i * 8, s + (size_t)i * 8);
  }
}

// ---- bf16 GEMM tile body (m97 structure): C = (A[M][1024] x B[N][1024]^T)*cs
template <int MF, int NF, typename TC>
__device__ __forceinline__ void gemm_body(const bf16_t* __restrict__ A,
                                          const bf16_t* __restrict__ B,
                                          TC* __restrict__ C,
                                          int ldC, int bm, int bn, float cs) {
  constexpr int BM = 32 * MF, BN = 32 * NF;
  __shared__ alignas(16) bf16_t As[BM][64];
  __shared__ alignas(16) bf16_t Bs[BN][64];
  const int tid  = threadIdx.x;
  const int lane = tid & 63, w = tid >> 6;
  const int g = lane >> 4, l15 = lane & 15;
  const int wr = w >> 1, wc = w & 1;

  f32x4 acc[MF][NF] = {};

  for (int kt = 0; kt < 1024; kt += 64) {
    if (kt) __syncthreads();
#pragma unroll
    for (int p = 0; p < MF; ++p) {
      int s = p * 256 + tid;
      int row = s >> 3, c = s & 7;
      int cg = c ^ (row & 7);
      gld_lds16(&A[(size_t)(bm + row) * 1024 + kt + cg * 8], &As[0][0] + s * 8);
    }
#pragma unroll
    for (int p = 0; p < NF; ++p) {
      int s = p * 256 + tid;
      int row = s >> 3, c = s & 7;
      int cg = c ^ (row & 7);
      gld_lds16(&B[(size_t)(bn + row) * 1024 + kt + cg * 8], &Bs[0][0] + s * 8);
    }
    asm volatile("s_waitcnt vmcnt(0)" ::: "memory");
    __syncthreads();

#pragma unroll
    for (int hh = 0; hh < 2; ++hh) {
      bf16x8 af[MF], bfr[NF];
#pragma unroll
      for (int m = 0; m < MF; ++m) {
        int row = wr * (16 * MF) + m * 16 + l15;
        af[m] = *(const bf16x8*)(&As[0][0] + row * 64 + (((hh * 4 + g) ^ (row & 7)) * 8));
      }
#pragma unroll
      for (int n = 0; n < NF; ++n) {
        int row = wc * (16 * NF) + n * 16 + l15;
        bfr[n] = *(const bf16x8*)(&Bs[0][0] + row * 64 + (((hh * 4 + g) ^ (row & 7)) * 8));
      }
#pragma unroll
      for (int m = 0; m < MF; ++m)
#pragma unroll
        for (int n = 0; n < NF; ++n)
          acc[m][n] = __builtin_amdgcn_mfma_f32_16x16x32_bf16(af[m], bfr[n], acc[m][n], 0, 0, 0);
    }
  }

#pragma unroll
  for (int m = 0; m < MF; ++m)
#pragma unroll
    for (int n = 0; n < NF; ++n)
#pragma unroll
      for (int r = 0; r < 4; ++r) {
        int row = bm + wr * (16 * MF) + m * 16 + g * 4 + r;
        int col = bn + wc * (16 * NF) + n * 16 + l15;
        C[(size_t)row * ldC + col] = (TC)(acc[m][n][r] * cs);
      }
}

// ---- fused Q/K/V projections: one launch, 768 blocks (3 blocks/CU) ----
__global__ __launch_bounds__(256) void proj_qkv(
    const bf16_t* __restrict__ qb, const bf16_t* __restrict__ kb,
    const bf16_t* __restrict__ vb,
    const bf16_t* __restrict__ Wqb, const bf16_t* __restrict__ Wkb,
    const bf16_t* __restrict__ Wvb,
    bf16_t* Qp, bf16_t* Kp, bf16_t* Vt) {
  const int bid = blockIdx.x;
  const int which = bid >> 8, t = bid & 255;
  const bf16_t *A, *B; bf16_t* C; int ldC, bm, bn; float cs;
  if (which == 0) {
    A = qb;  B = Wqb; C = Qp; ldC = 1024;
    bm = (t >> 3) * 128; bn = (t & 7) * 128; cs = QSCALE_F;
  } else if (which == 1) {
    A = kb;  B = Wkb; C = Kp; ldC = 1024;
    bm = (t >> 3) * 128; bn = (t & 7) * 128; cs = 1.0f;
  } else {
    A = Wvb; B = vb;  C = Vt; ldC = 4096;
    bm = (t >> 5) * 128; bn = (t & 31) * 128; cs = 1.0f;
  }
  gemm_body<4, 4, bf16_t>(A, B, C, ldC, bm, bn, cs);
}

// ---- final GEMM: out = Oa @ Wo^T, 64x128 tiles (grid 8x64, 2 blocks/CU) ----
__global__ __launch_bounds__(256) void gemm_fin(const bf16_t* __restrict__ A,
                                                const bf16_t* __restrict__ B,
                                                float* __restrict__ C) {
  gemm_body<2, 4, float>(A, B, C, 1024, blockIdx.y * 64, blockIdx.x * 128, 1.0f);
}

// ---- fallback GEMM (fp32 staging, used only if ws too small) ----
template <typename TA, typename TB, typename TC>
__global__ __launch_bounds__(256) void gemm_bt(const TA* __restrict__ A,
                                               const TB* __restrict__ B,
                                               TC* __restrict__ C,
                                               int M, int N, int K, float cscale) {
  __shared__ alignas(16) bf16_t As[128][40];
  __shared__ alignas(16) bf16_t Bs[128][40];
  const int tid  = threadIdx.x;
  const int lane = tid & 63, w = tid >> 6;
  const int g = lane >> 4, l15 = lane & 15;
  const int wr = w >> 1, wc = w & 1;
  const int bm = blockIdx.y * 128, bn = blockIdx.x * 128;

  f32x4 acc[4][4] = {};

  for (int kt = 0; kt < K; kt += 32) {
    __syncthreads();
#pragma unroll
    for (int i = 0; i < 2; ++i) {
      int vv  = tid + i * 256;
      int row = vv >> 2, c8 = (vv & 3) * 8;
      stage8(&As[row][c8], &A[(size_t)(bm + row) * K + kt + c8]);
      stage8(&Bs[row][c8], &B[(size_t)(bn + row) * K + kt + c8]);
    }
    __syncthreads();

    bf16x8 af[4], bfr[4];
#pragma unroll
    for (int m = 0; m < 4; ++m)
      af[m] = *(const bf16x8*)&As[wr * 64 + m * 16 + l15][g * 8];
#pragma unroll
    for (int n = 0; n < 4; ++n)
      bfr[n] = *(const bf16x8*)&Bs[wc * 64 + n * 16 + l15][g * 8];
#pragma unroll
    for (int m = 0; m < 4; ++m)
#pragma unroll
      for (int n = 0; n < 4; ++n)
        acc[m][n] = __builtin_amdgcn_mfma_f32_16x16x32_bf16(af[m], bfr[n], acc[m][n], 0, 0, 0);
  }

#pragma unroll
  for (int m = 0; m < 4; ++m)
#pragma unroll
    for (int n = 0; n < 4; ++n)
#pragma unroll
      for (int r = 0; r < 4; ++r) {
        int row = bm + wr * 64 + m * 16 + g * 4 + r;
        int col = bn + wc * 64 + n * 16 + l15;
        C[(size_t)row * N + col] = (TC)(acc[m][n][r] * cscale);
      }
}

// ---- Flash attention, causal, online softmax (log2 domain, pre-scaled Q) ----
// QBLK=128, KVBLK=64, 8 waves (512 thr), grid 512 (2 blocks/CU, grid-capped).
// Round-15 structure + two latency cuts:
//  (1) 2-deep prefetch (round-6 pattern): K[3]/V[4] slots, issue(min(j+2,
//      nt-1)), wait vmcnt(2) -- loads get two phases to land. Slot audit:
//      issue at phase j writes K slot (j+2)%3 (K_{j-1} read done pre-barrier),
//      V slot (j+2)%4 (V_{j-2} read done pre-barrier); clamped re-issue keeps
//      vmcnt uniform and rewrites identical bytes.
//  (2) tree-structured pmax/ps reductions (depth 4 vs serial 16).
__global__ __launch_bounds__(512) void attn_fwd(const bf16_t* __restrict__ Qp,
                                                const bf16_t* __restrict__ Kp,
                                                const bf16_t* __restrict__ Vt,
                                                bf16_t* __restrict__ Oattn) {
  const int bid = blockIdx.x;          // 0..511
  const int h   = bid & 15;            // (bid+256)&15 == h: CU pair same head
  const int idx = bid >> 4;            // 0..31
  const int qi  = idx < 16 ? 31 - idx : idx - 16;  // pair (31-i, i) per CU
  const int tid = threadIdx.x, lane = tid & 63, w = tid >> 6;
  const int g = lane >> 4, l15 = lane & 15;
  const int qrow = qi * 128 + w * 16;  // wave w owns 16 q-rows

  __shared__ alignas(16) bf16_t Ks[3][64][64];   // 24 KB, swizzled
  __shared__ alignas(16) bf16_t Vs[4][64][64];   // 32 KB, swizzled
  __shared__ alignas(16) bf16_t Plds[8][16][72]; // 18 KB, [q][k], 144B stride

  bf16x8 qf[2];
  {
    const bf16_t* qp = &Qp[(size_t)(qrow + l15) * E_DIM + h * 64 + g * 8];
    qf[0] = *(const bf16x8*)qp;
    qf[1] = *(const bf16x8*)(qp + 32);
  }

  // staging: 512 threads x 16B = one 64x64 bf16 tile per (K,V) issue
  const int row0 = tid >> 3, c0 = tid & 7;
  const int cgo = (c0 ^ (row0 & 7)) * 8;           // source-side swizzle
  const bf16_t* srcK = Kp + (size_t)row0 * E_DIM + h * 64 + cgo;
  const bf16_t* srcV = Vt + (size_t)(h * 64 + row0) * T_DIM + cgo;
  bf16_t* KsAll = &Ks[0][0][0];
  bf16_t* VsAll = &Vs[0][0][0];
  const size_t KADV = (size_t)64 * E_DIM;          // 65536: t*KADV is a shift
  const int nt = 2 * qi + 2;

  auto issue = [&](int t) {
    gld_lds16(srcK + (size_t)t * KADV, KsAll + (t % 3) * 4096 + tid * 8);
    gld_lds16(srcV + (size_t)t * 64,   VsAll + (t & 3) * 4096 + tid * 8);
  };

  f32x4 acc[4] = {};          // acc[c][r]: O^T[d = c*16 + g*4 + r][q = l15]
  float m_s = -1e30f, l_p = 0.f;   // m row-uniform; l per-lane partial

  auto pv = [&](int t) {
    const char* Vb = (const char*)(VsAll + (t & 3) * 4096);
    bf16x8 pf0 = *(const bf16x8*)&Plds[w][l15][g * 8];        // k = g*8..+7
    bf16x8 pf1 = *(const bf16x8*)&Plds[w][l15][32 + g * 8];   // k = 32+g*8..
#pragma unroll
    for (int c = 0; c < 4; ++c) {
      const int vr = c * 16 + l15;
      const char* rp = Vb + vr * 128;
      const int sw = (vr & 7) << 4;
      bf16x8 v0 = *(const bf16x8*)(rp + ((g * 16) ^ sw));
      bf16x8 v1 = *(const bf16x8*)(rp + ((64 + g * 16) ^ sw));
      acc[c] = __builtin_amdgcn_mfma_f32_16x16x32_bf16(v0, pf0, acc[c], 0, 0, 0);
      acc[c] = __builtin_amdgcn_mfma_f32_16x16x32_bf16(v1, pf1, acc[c], 0, 0, 0);
    }
  };

  // prologue: tiles 0 and 1 in flight (nt >= 2 always)
  issue(0);
  issue(min(1, nt - 1));

  for (int j = 0; j < nt; ++j) {
    // own K_j,V_j landed; up to 2 newer issues (j+1, j+2) stay in flight
    asm volatile("s_waitcnt vmcnt(2)" ::: "memory");
    block_sync();                 // all waves' K_j,V_j resident; phase j-1 done
    issue(min(j + 2, nt - 1));    // 2-ahead; clamp keeps vmcnt uniform

    __builtin_amdgcn_s_setprio(1);
    if (j > 0) pv(j - 1);         // PV_{j-1}, one phase late (before rescale!)

    // S^T = K (Q*SCALE*log2e)^T from Ks[j%3]: s[j16][r] is
    // (k = j*64 + 16*j16 + 4*g + r, q = qrow + l15)
    const char* Kb = (const char*)(KsAll + (j % 3) * 4096);
    f32x4 s[4] = {};
#pragma unroll
    for (int j16 = 0; j16 < 4; ++j16) {
      const int r0 = j16 * 16 + l15;
      const char* rp = Kb + r0 * 128;
      const int sw = (r0 & 7) << 4;
      bf16x8 k0 = *(const bf16x8*)(rp + ((g * 16) ^ sw));
      bf16x8 k1 = *(const bf16x8*)(rp + ((64 + g * 16) ^ sw));
      s[j16] = __builtin_amdgcn_mfma_f32_16x16x32_bf16(k0, qf[0], s[j16], 0, 0, 0);
      s[j16] = __builtin_amdgcn_mfma_f32_16x16x32_bf16(k1, qf[1], s[j16], 0, 0, 0);
    }
    __builtin_amdgcn_s_setprio(0);

    // causal mask: k > q, on any tile overlapping/above this wave's rows
    const int kb = j * 64;
    if (kb + 63 > qrow) {
#pragma unroll
      for (int j16 = 0; j16 < 4; ++j16)
#pragma unroll
        for (int r = 0; r < 4; ++r)
          if (kb + j16 * 16 + g * 4 + r > qrow + l15) s[j16][r] = -1e30f;
    }

    // online softmax; pmax as depth-4 tree (serial 16-chain was on the
    // critical path between QK and P-write)
    float x0 = fmaxf(s[0][0], s[0][1]), x1 = fmaxf(s[0][2], s[0][3]);
    float x2 = fmaxf(s[1][0], s[1][1]), x3 = fmaxf(s[1][2], s[1][3]);
    float x4 = fmaxf(s[2][0], s[2][1]), x5 = fmaxf(s[2][2], s[2][3]);
    float x6 = fmaxf(s[3][0], s[3][1]), x7 = fmaxf(s[3][2], s[3][3]);
    float y0 = fmaxf(x0, x1), y1 = fmaxf(x2, x3);
    float y2 = fmaxf(x4, x5), y3 = fmaxf(x6, x7);
    float pmax = fmaxf(fmaxf(y0, y1), fmaxf(y2, y3));

    if (!__all(pmax <= m_s + 11.0f)) {
      float rm = fmaxf(pmax, __shfl_xor(pmax, 16));
      rm = fmaxf(rm, __shfl_xor(rm, 32));     // row-uniform max
      float mn = fmaxf(m_s, rm);
      float sc = fexp2(m_s - mn);
      m_s = mn;
      l_p *= sc;
#pragma unroll
      for (int c = 0; c < 4; ++c)
#pragma unroll
        for (int r = 0; r < 4; ++r) acc[c][r] *= sc;
    }

#pragma unroll
    for (int j16 = 0; j16 < 4; ++j16)
#pragma unroll
      for (int r = 0; r < 4; ++r)
        s[j16][r] = fexp2(s[j16][r] - m_s);

    // per-lane partial sum as depth-4 tree
    {
      float a0 = s[0][0] + s[0][1], a1 = s[0][2] + s[0][3];
      float a2 = s[1][0] + s[1][1], a3 = s[1][2] + s[1][3];
      float a4 = s[2][0] + s[2][1], a5 = s[2][2] + s[2][3];
      float a6 = s[3][0] + s[3][1], a7 = s[3][2] + s[3][3];
      float b0 = a0 + a1, b1 = a2 + a3, b2 = a4 + a5, b3 = a6 + a7;
      l_p += (b0 + b1) + (b2 + b3);
    }

    // P -> LDS [q][k]: per j16 the 4 r-values are k-consecutive -> b64
#pragma unroll
    for (int j16 = 0; j16 < 4; ++j16) {
      bf16x4 pk;
      pk[0] = (bf16_t)s[j16][0]; pk[1] = (bf16_t)s[j16][1];
      pk[2] = (bf16_t)s[j16][2]; pk[3] = (bf16_t)s[j16][3];
      *(bf16x4*)&Plds[w][l15][j16 * 16 + g * 4] = pk;
    }
  }

  // epilogue: PV for the last tile, one quad l-reduce, O^T write
  pv(nt - 1);

  float lt = l_p;
  lt += __shfl_xor(lt, 16);
  lt += __shfl_xor(lt, 32);
  const float inv = 1.0f / lt;
#pragma unroll
  for (int c = 0; c < 4; ++c) {
    bf16x4 o;
#pragma unroll
    for (int r = 0; r < 4; ++r) o[r] = (bf16_t)(acc[c][r] * inv);
    *(bf16x4*)&Oattn[(size_t)(qrow + l15) * E_DIM + h * 64 + c * 16 + g * 4] = o;
  }
}

extern "C" void kernel_launch(void* const* d_in, const int* in_sizes, int n_in,
                              void* d_out, int out_size, void* d_ws, size_t ws_size,
                              hipStream_t stream) {
  const float* q  = (const float*)d_in[0];
  const float* k  = (const float*)d_in[1];
  const float* v  = (const float*)d_in[2];
  const float* Wq = (const float*)d_in[3];
  const float* Wk = (const float*)d_in[4];
  const float* Wv = (const float*)d_in[5];
  const float* Wo = (const float*)d_in[6];
  float* out = (float*)d_out;

  const size_t TE = (size_t)T_DIM * E_DIM;   // 4M elems
  const size_t EE = (size_t)E_DIM * E_DIM;   // 1M elems
  dim3 blk(256);

  if (ws_size >= (size_t)56 * 1024 * 1024) {
    bf16_t* qb  = (bf16_t*)d_ws;          // reused as Oa after projections
    bf16_t* kb  = qb + TE;
    bf16_t* vb  = kb + TE;
    bf16_t* Wqb = vb + TE;
    bf16_t* Wkb = Wqb + EE;
    bf16_t* Wvb = Wkb + EE;
    bf16_t* Wob = Wvb + EE;
    bf16_t* Qp  = Wob + EE;
    bf16_t* Kp  = Qp + TE;
    bf16_t* Vt  = Kp + TE;                // [E][T]
    bf16_t* Oa  = qb;                     // alias

    cvt_all<<<2048, blk, 0, stream>>>(q, k, v, Wq, Wk, Wv, Wo,
                                      qb, kb, vb, Wqb, Wkb, Wvb, Wob);
    proj_qkv<<<dim3(768), blk, 0, stream>>>(qb, kb, vb, Wqb, Wkb, Wvb, Qp, Kp, Vt);
    attn_fwd<<<dim3(512), dim3(512), 0, stream>>>(Qp, Kp, Vt, Oa);
    gemm_fin<<<dim3(8, 64), blk, 0, stream>>>(Oa, Wob, out);
  } else {
    bf16_t* Qp = (bf16_t*)d_ws;
    bf16_t* Kp = Qp + TE;
    bf16_t* Vt = Kp + TE;
    bf16_t* Oa = Vt + TE;
    gemm_bt<float, float, bf16_t><<<dim3(8, 32), blk, 0, stream>>>(q, Wq, Qp, T_DIM, E_DIM, E_DIM, QSCALE_F);
    gemm_bt<float, float, bf16_t><<<dim3(8, 32), blk, 0, stream>>>(k, Wk, Kp, T_DIM, E_DIM, E_DIM, 1.0f);
    gemm_bt<float, float, bf16_t><<<dim3(32, 8), blk, 0, stream>>>(Wv, v, Vt, E_DIM, T_DIM, E_DIM, 1.0f);
    attn_fwd<<<dim3(512), dim3(512), 0, stream>>>(Qp, Kp, Vt, Oa);
    gemm_bt<bf16_t, float, float><<<dim3(8, 32), blk, 0, stream>>>(Oa, Wo, out, T_DIM, E_DIM, E_DIM, 1.0f);
  }
}

// Round 17
// 123.853 us; speedup vs baseline: 1.1446x; 1.1446x over previous
//
#include <hip/hip_runtime.h>
#include <hip/hip_bf16.h>

// Problem constants (B=1)
#define T_DIM 4096
#define E_DIM 1024
#define H_DIM 16
#define HD_DIM 64
#define LOG2E_F 1.4426950408889634f
#define QSCALE_F (0.125f * LOG2E_F)   // SCALE * log2(e), folded into Qp

typedef __bf16 bf16_t;
typedef __bf16 bf16x8 __attribute__((ext_vector_type(8)));
typedef __bf16 bf16x4 __attribute__((ext_vector_type(4)));
typedef float  f32x4  __attribute__((ext_vector_type(4)));

// ---- helpers ----
__device__ inline void stage8(bf16_t* dst, const float* src) {
  const f32x4* s4 = (const f32x4*)src;
  f32x4 a = s4[0], b = s4[1];
  bf16x8 o;
  o[0] = (bf16_t)a[0]; o[1] = (bf16_t)a[1]; o[2] = (bf16_t)a[2]; o[3] = (bf16_t)a[3];
  o[4] = (bf16_t)b[0]; o[5] = (bf16_t)b[1]; o[6] = (bf16_t)b[2]; o[7] = (bf16_t)b[3];
  *(bf16x8*)dst = o;
}
__device__ inline void stage8(bf16_t* dst, const bf16_t* src) {
  *(bf16x8*)dst = *(const bf16x8*)src;
}

__device__ inline void gld_lds16(const bf16_t* g, bf16_t* l) {
  __builtin_amdgcn_global_load_lds(
      (const __attribute__((address_space(1))) unsigned int*)g,
      (__attribute__((address_space(3))) unsigned int*)l, 16, 0, 0);
}

__device__ inline float fexp2(float x) {  // raw v_exp_f32 (exp2)
  float r;
  asm("v_exp_f32 %0, %1" : "=v"(r) : "v"(x));
  return r;
}

// raw barrier (no implicit vmcnt(0) drain) + compiler memory fence
__device__ inline void block_sync() {
  asm volatile("" ::: "memory");
  __builtin_amdgcn_s_barrier();
  asm volatile("" ::: "memory");
}

// ---- fp32 -> bf16 conversion for all 7 inputs (one launch) ----
__global__ __launch_bounds__(256) void cvt_all(
    const float* __restrict__ q, const float* __restrict__ k, const float* __restrict__ v,
    const float* __restrict__ Wq, const float* __restrict__ Wk,
    const float* __restrict__ Wv, const float* __restrict__ Wo,
    bf16_t* qb, bf16_t* kb, bf16_t* vb,
    bf16_t* Wqb, bf16_t* Wkb, bf16_t* Wvb, bf16_t* Wob) {
  for (int u = blockIdx.x * 256 + threadIdx.x; u < 2097152; u += gridDim.x * 256) {
    const float* s; bf16_t* d; int i;
    if (u < 1572864) {
      int seg = u >> 19, off = u & 524287;
      s = seg == 0 ? q : (seg == 1 ? k : v);
      d = seg == 0 ? qb : (seg == 1 ? kb : vb);
      i = off;
    } else {
      int w = u - 1572864;
      int seg = w >> 17, off = w & 131071;
      s = seg == 0 ? Wq : seg == 1 ? Wk : seg == 2 ? Wv : Wo;
      d = seg == 0 ? Wqb : seg == 1 ? Wkb : seg == 2 ? Wvb : Wob;
      i = off;
    }
    stage8(d + (size_t)i * 8, s + (size_t)i * 8);
  }
}

// ---- bf16 GEMM tile body (m97 structure): C = (A[M][1024] x B[N][1024]^T)*cs
template <int MF, int NF, typename TC>
__device__ __forceinline__ void gemm_body(const bf16_t* __restrict__ A,
                                          const bf16_t* __restrict__ B,
                                          TC* __restrict__ C,
                                          int ldC, int bm, int bn, float cs) {
  constexpr int BM = 32 * MF, BN = 32 * NF;
  __shared__ alignas(16) bf16_t As[BM][64];
  __shared__ alignas(16) bf16_t Bs[BN][64];
  const int tid  = threadIdx.x;
  const int lane = tid & 63, w = tid >> 6;
  const int g = lane >> 4, l15 = lane & 15;
  const int wr = w >> 1, wc = w & 1;

  f32x4 acc[MF][NF] = {};

  for (int kt = 0; kt < 1024; kt += 64) {
    if (kt) __syncthreads();
#pragma unroll
    for (int p = 0; p < MF; ++p) {
      int s = p * 256 + tid;
      int row = s >> 3, c = s & 7;
      int cg = c ^ (row & 7);
      gld_lds16(&A[(size_t)(bm + row) * 1024 + kt + cg * 8], &As[0][0] + s * 8);
    }
#pragma unroll
    for (int p = 0; p < NF; ++p) {
      int s = p * 256 + tid;
      int row = s >> 3, c = s & 7;
      int cg = c ^ (row & 7);
      gld_lds16(&B[(size_t)(bn + row) * 1024 + kt + cg * 8], &Bs[0][0] + s * 8);
    }
    asm volatile("s_waitcnt vmcnt(0)" ::: "memory");
    __syncthreads();

#pragma unroll
    for (int hh = 0; hh < 2; ++hh) {
      bf16x8 af[MF], bfr[NF];
#pragma unroll
      for (int m = 0; m < MF; ++m) {
        int row = wr * (16 * MF) + m * 16 + l15;
        af[m] = *(const bf16x8*)(&As[0][0] + row * 64 + (((hh * 4 + g) ^ (row & 7)) * 8));
      }
#pragma unroll
      for (int n = 0; n < NF; ++n) {
        int row = wc * (16 * NF) + n * 16 + l15;
        bfr[n] = *(const bf16x8*)(&Bs[0][0] + row * 64 + (((hh * 4 + g) ^ (row & 7)) * 8));
      }
#pragma unroll
      for (int m = 0; m < MF; ++m)
#pragma unroll
        for (int n = 0; n < NF; ++n)
          acc[m][n] = __builtin_amdgcn_mfma_f32_16x16x32_bf16(af[m], bfr[n], acc[m][n], 0, 0, 0);
    }
  }

#pragma unroll
  for (int m = 0; m < MF; ++m)
#pragma unroll
    for (int n = 0; n < NF; ++n)
#pragma unroll
      for (int r = 0; r < 4; ++r) {
        int row = bm + wr * (16 * MF) + m * 16 + g * 4 + r;
        int col = bn + wc * (16 * NF) + n * 16 + l15;
        C[(size_t)row * ldC + col] = (TC)(acc[m][n][r] * cs);
      }
}

// ---- fused Q/K/V projections: one launch, 768 blocks (3 blocks/CU) ----
__global__ __launch_bounds__(256) void proj_qkv(
    const bf16_t* __restrict__ qb, const bf16_t* __restrict__ kb,
    const bf16_t* __restrict__ vb,
    const bf16_t* __restrict__ Wqb, const bf16_t* __restrict__ Wkb,
    const bf16_t* __restrict__ Wvb,
    bf16_t* Qp, bf16_t* Kp, bf16_t* Vt) {
  const int bid = blockIdx.x;
  const int which = bid >> 8, t = bid & 255;
  const bf16_t *A, *B; bf16_t* C; int ldC, bm, bn; float cs;
  if (which == 0) {
    A = qb;  B = Wqb; C = Qp; ldC = 1024;
    bm = (t >> 3) * 128; bn = (t & 7) * 128; cs = QSCALE_F;
  } else if (which == 1) {
    A = kb;  B = Wkb; C = Kp; ldC = 1024;
    bm = (t >> 3) * 128; bn = (t & 7) * 128; cs = 1.0f;
  } else {
    A = Wvb; B = vb;  C = Vt; ldC = 4096;
    bm = (t >> 5) * 128; bn = (t & 31) * 128; cs = 1.0f;
  }
  gemm_body<4, 4, bf16_t>(A, B, C, ldC, bm, bn, cs);
}

// ---- final GEMM: out = Oa @ Wo^T, 64x128 tiles (grid 8x64, 2 blocks/CU) ----
__global__ __launch_bounds__(256) void gemm_fin(const bf16_t* __restrict__ A,
                                                const bf16_t* __restrict__ B,
                                                float* __restrict__ C) {
  gemm_body<2, 4, float>(A, B, C, 1024, blockIdx.y * 64, blockIdx.x * 128, 1.0f);
}

// ---- fallback GEMM (fp32 staging, used only if ws too small) ----
template <typename TA, typename TB, typename TC>
__global__ __launch_bounds__(256) void gemm_bt(const TA* __restrict__ A,
                                               const TB* __restrict__ B,
                                               TC* __restrict__ C,
                                               int M, int N, int K, float cscale) {
  __shared__ alignas(16) bf16_t As[128][40];
  __shared__ alignas(16) bf16_t Bs[128][40];
  const int tid  = threadIdx.x;
  const int lane = tid & 63, w = tid >> 6;
  const int g = lane >> 4, l15 = lane & 15;
  const int wr = w >> 1, wc = w & 1;
  const int bm = blockIdx.y * 128, bn = blockIdx.x * 128;

  f32x4 acc[4][4] = {};

  for (int kt = 0; kt < K; kt += 32) {
    __syncthreads();
#pragma unroll
    for (int i = 0; i < 2; ++i) {
      int vv  = tid + i * 256;
      int row = vv >> 2, c8 = (vv & 3) * 8;
      stage8(&As[row][c8], &A[(size_t)(bm + row) * K + kt + c8]);
      stage8(&Bs[row][c8], &B[(size_t)(bn + row) * K + kt + c8]);
    }
    __syncthreads();

    bf16x8 af[4], bfr[4];
#pragma unroll
    for (int m = 0; m < 4; ++m)
      af[m] = *(const bf16x8*)&As[wr * 64 + m * 16 + l15][g * 8];
#pragma unroll
    for (int n = 0; n < 4; ++n)
      bfr[n] = *(const bf16x8*)&Bs[wc * 64 + n * 16 + l15][g * 8];
#pragma unroll
    for (int m = 0; m < 4; ++m)
#pragma unroll
      for (int n = 0; n < 4; ++n)
        acc[m][n] = __builtin_amdgcn_mfma_f32_16x16x32_bf16(af[m], bfr[n], acc[m][n], 0, 0, 0);
  }

#pragma unroll
  for (int m = 0; m < 4; ++m)
#pragma unroll
    for (int n = 0; n < 4; ++n)
#pragma unroll
      for (int r = 0; r < 4; ++r) {
        int row = bm + wr * 64 + m * 16 + g * 4 + r;
        int col = bn + wc * 64 + n * 16 + l15;
        C[(size_t)row * N + col] = (TC)(acc[m][n][r] * cscale);
      }
}

// ---- Flash attention, causal, online softmax (log2 domain, pre-scaled Q) ----
// ROUND-15 structure (best known: 8 waves/512thr, QBLK=128, KVBLK=64, single
// barrier/phase, delayed PV, K double-/V triple-buffer, 1-ahead issue,
// vmcnt(0) wait -- round 16 proved deeper prefetch regresses).
// VALU diet this round:
//  (1) l via MFMA ones-trick: l[q] = sum_k P[k][q] = mfma(ones, P) -- one
//      extra acc fragment + 2 MFMA in the PV cluster reusing pf0/pf1;
//      deletes the 15-op add tree AND the epilogue cross-lane reduce.
//  (2) pmax via nested fmaxf triples (v_max3): 16 values in 7 ops.
__global__ __launch_bounds__(512) void attn_fwd(const bf16_t* __restrict__ Qp,
                                                const bf16_t* __restrict__ Kp,
                                                const bf16_t* __restrict__ Vt,
                                                bf16_t* __restrict__ Oattn) {
  const int bid = blockIdx.x;          // 0..511
  const int h   = bid & 15;            // (bid+256)&15 == h: CU pair same head
  const int idx = bid >> 4;            // 0..31
  const int qi  = idx < 16 ? 31 - idx : idx - 16;  // pair (31-i, i) per CU
  const int tid = threadIdx.x, lane = tid & 63, w = tid >> 6;
  const int g = lane >> 4, l15 = lane & 15;
  const int qrow = qi * 128 + w * 16;  // wave w owns 16 q-rows

  __shared__ alignas(16) bf16_t Ks[2][64][64];   // 16 KB, swizzled
  __shared__ alignas(16) bf16_t Vs[3][64][64];   // 24 KB, swizzled
  __shared__ alignas(16) bf16_t Plds[8][16][72]; // 18 KB, [q][k], 144B stride

  bf16x8 qf[2];
  {
    const bf16_t* qp = &Qp[(size_t)(qrow + l15) * E_DIM + h * 64 + g * 8];
    qf[0] = *(const bf16x8*)qp;
    qf[1] = *(const bf16x8*)(qp + 32);
  }

  bf16x8 ones;
#pragma unroll
  for (int i = 0; i < 8; ++i) ones[i] = (bf16_t)1.0f;

  // staging: 512 threads x 16B = one 64x64 bf16 tile per (K,V) issue
  const int row0 = tid >> 3, c0 = tid & 7;
  const int cgo = (c0 ^ (row0 & 7)) * 8;           // source-side swizzle
  const bf16_t* srcK = Kp + (size_t)row0 * E_DIM + h * 64 + cgo;
  const bf16_t* srcV = Vt + (size_t)(h * 64 + row0) * T_DIM + cgo;
  bf16_t* KsAll = &Ks[0][0][0];
  bf16_t* VsAll = &Vs[0][0][0];
  const size_t KADV = (size_t)64 * E_DIM;
  const int nt = 2 * qi + 2;

  auto issue = [&](int t) {
    gld_lds16(srcK + (size_t)t * KADV, KsAll + (t & 1) * 4096 + tid * 8);
    gld_lds16(srcV + (size_t)t * 64,   VsAll + (t % 3) * 4096 + tid * 8);
  };

  f32x4 acc[4] = {};          // acc[c][r]: O^T[d = c*16 + g*4 + r][q = l15]
  f32x4 acc_l = {};           // ones-trick row sums: acc_l[r] == l[q], all r
  float m_s = -1e30f;         // row-uniform running max

  auto pv = [&](int t) {
    const char* Vb = (const char*)(VsAll + (t % 3) * 4096);
    bf16x8 pf0 = *(const bf16x8*)&Plds[w][l15][g * 8];        // k = g*8..+7
    bf16x8 pf1 = *(const bf16x8*)&Plds[w][l15][32 + g * 8];   // k = 32+g*8..
#pragma unroll
    for (int c = 0; c < 4; ++c) {
      const int vr = c * 16 + l15;
      const char* rp = Vb + vr * 128;
      const int sw = (vr & 7) << 4;
      bf16x8 v0 = *(const bf16x8*)(rp + ((g * 16) ^ sw));
      bf16x8 v1 = *(const bf16x8*)(rp + ((64 + g * 16) ^ sw));
      acc[c] = __builtin_amdgcn_mfma_f32_16x16x32_bf16(v0, pf0, acc[c], 0, 0, 0);
      acc[c] = __builtin_amdgcn_mfma_f32_16x16x32_bf16(v1, pf1, acc[c], 0, 0, 0);
    }
    // l[q] += sum_k P[k][q] on the MFMA pipe (same pf fragments)
    acc_l = __builtin_amdgcn_mfma_f32_16x16x32_bf16(ones, pf0, acc_l, 0, 0, 0);
    acc_l = __builtin_amdgcn_mfma_f32_16x16x32_bf16(ones, pf1, acc_l, 0, 0, 0);
  };

  issue(0);

  for (int j = 0; j < nt; ++j) {
    asm volatile("s_waitcnt vmcnt(0)" ::: "memory");
    block_sync();                 // all waves' K_j,V_j resident; phase j-1 done
    if (j + 1 < nt) issue(j + 1);

    __builtin_amdgcn_s_setprio(1);
    if (j > 0) pv(j - 1);         // PV_{j-1}, one phase late (before rescale!)

    // S^T = K (Q*SCALE*log2e)^T from Ks[j&1]: s[j16][r] is
    // (k = j*64 + 16*j16 + 4*g + r, q = qrow + l15)
    const char* Kb = (const char*)(KsAll + (j & 1) * 4096);
    f32x4 s[4] = {};
#pragma unroll
    for (int j16 = 0; j16 < 4; ++j16) {
      const int r0 = j16 * 16 + l15;
      const char* rp = Kb + r0 * 128;
      const int sw = (r0 & 7) << 4;
      bf16x8 k0 = *(const bf16x8*)(rp + ((g * 16) ^ sw));
      bf16x8 k1 = *(const bf16x8*)(rp + ((64 + g * 16) ^ sw));
      s[j16] = __builtin_amdgcn_mfma_f32_16x16x32_bf16(k0, qf[0], s[j16], 0, 0, 0);
      s[j16] = __builtin_amdgcn_mfma_f32_16x16x32_bf16(k1, qf[1], s[j16], 0, 0, 0);
    }
    __builtin_amdgcn_s_setprio(0);

    // causal mask: k > q, on any tile overlapping/above this wave's rows
    const int kb = j * 64;
    if (kb + 63 > qrow) {
#pragma unroll
      for (int j16 = 0; j16 < 4; ++j16)
#pragma unroll
        for (int r = 0; r < 4; ++r)
          if (kb + j16 * 16 + g * 4 + r > qrow + l15) s[j16][r] = -1e30f;
    }

    // online softmax; pmax via nested max-triples (v_max3, 7 ops for 16)
    float t0 = fmaxf(fmaxf(s[0][0], s[0][1]), s[0][2]);
    float t1 = fmaxf(fmaxf(s[0][3], s[1][0]), s[1][1]);
    float t2 = fmaxf(fmaxf(s[1][2], s[1][3]), s[2][0]);
    float t3 = fmaxf(fmaxf(s[2][1], s[2][2]), s[2][3]);
    float t4 = fmaxf(fmaxf(s[3][0], s[3][1]), s[3][2]);
    float pmax = fmaxf(fmaxf(fmaxf(t0, t1), t2),
                       fmaxf(fmaxf(t3, t4), s[3][3]));

    if (!__all(pmax <= m_s + 11.0f)) {
      float rm = fmaxf(pmax, __shfl_xor(pmax, 16));
      rm = fmaxf(rm, __shfl_xor(rm, 32));     // row-uniform max
      float mn = fmaxf(m_s, rm);
      float sc = fexp2(m_s - mn);
      m_s = mn;
#pragma unroll
      for (int r = 0; r < 4; ++r) acc_l[r] *= sc;
#pragma unroll
      for (int c = 0; c < 4; ++c)
#pragma unroll
        for (int r = 0; r < 4; ++r) acc[c][r] *= sc;
    }

#pragma unroll
    for (int j16 = 0; j16 < 4; ++j16)
#pragma unroll
      for (int r = 0; r < 4; ++r)
        s[j16][r] = fexp2(s[j16][r] - m_s);

    // P -> LDS [q][k]: per j16 the 4 r-values are k-consecutive -> b64
#pragma unroll
    for (int j16 = 0; j16 < 4; ++j16) {
      bf16x4 pk;
      pk[0] = (bf16_t)s[j16][0]; pk[1] = (bf16_t)s[j16][1];
      pk[2] = (bf16_t)s[j16][2]; pk[3] = (bf16_t)s[j16][3];
      *(bf16x4*)&Plds[w][l15][j16 * 16 + g * 4] = pk;
    }
  }

  // epilogue: PV for the last tile; l comes straight from acc_l (no shfl)
  pv(nt - 1);

  const float inv = 1.0f / acc_l[0];
#pragma unroll
  for (int c = 0; c < 4; ++c) {
    bf16x4 o;
#pragma unroll
    for (int r = 0; r < 4; ++r) o[r] = (bf16_t)(acc[c][r] * inv);
    *(bf16x4*)&Oattn[(size_t)(qrow + l15) * E_DIM + h * 64 + c * 16 + g * 4] = o;
  }
}

extern "C" void kernel_launch(void* const* d_in, const int* in_sizes, int n_in,
                              void* d_out, int out_size, void* d_ws, size_t ws_size,
                              hipStream_t stream) {
  const float* q  = (const float*)d_in[0];
  const float* k  = (const float*)d_in[1];
  const float* v  = (const float*)d_in[2];
  const float* Wq = (const float*)d_in[3];
  const float* Wk = (const float*)d_in[4];
  const float* Wv = (const float*)d_in[5];
  const float* Wo = (const float*)d_in[6];
  float* out = (float*)d_out;

  const size_t TE = (size_t)T_DIM * E_DIM;   // 4M elems
  const size_t EE = (size_t)E_DIM * E_DIM;   // 1M elems
  dim3 blk(256);

  if (ws_size >= (size_t)56 * 1024 * 1024) {
    bf16_t* qb  = (bf16_t*)d_ws;          // reused as Oa after projections
    bf16_t* kb  = qb + TE;
    bf16_t* vb  = kb + TE;
    bf16_t* Wqb = vb + TE;
    bf16_t* Wkb = Wqb + EE;
    bf16_t* Wvb = Wkb + EE;
    bf16_t* Wob = Wvb + EE;
    bf16_t* Qp  = Wob + EE;
    bf16_t* Kp  = Qp + TE;
    bf16_t* Vt  = Kp + TE;                // [E][T]
    bf16_t* Oa  = qb;                     // alias

    cvt_all<<<2048, blk, 0, stream>>>(q, k, v, Wq, Wk, Wv, Wo,
                                      qb, kb, vb, Wqb, Wkb, Wvb, Wob);
    proj_qkv<<<dim3(768), blk, 0, stream>>>(qb, kb, vb, Wqb, Wkb, Wvb, Qp, Kp, Vt);
    attn_fwd<<<dim3(512), dim3(512), 0, stream>>>(Qp, Kp, Vt, Oa);
    gemm_fin<<<dim3(8, 64), blk, 0, stream>>>(Oa, Wob, out);
  } else {
    bf16_t* Qp = (bf16_t*)d_ws;
    bf16_t* Kp = Qp + TE;
    bf16_t* Vt = Kp + TE;
    bf16_t* Oa = Vt + TE;
    gemm_bt<float, float, bf16_t><<<dim3(8, 32), blk, 0, stream>>>(q, Wq, Qp, T_DIM, E_DIM, E_DIM, QSCALE_F);
    gemm_bt<float, float, bf16_t><<<dim3(8, 32), blk, 0, stream>>>(k, Wk, Kp, T_DIM, E_DIM, E_DIM, 1.0f);
    gemm_bt<float, float, bf16_t><<<dim3(32, 8), blk, 0, stream>>>(Wv, v, Vt, E_DIM, T_DIM, E_DIM, 1.0f);
    attn_fwd<<<dim3(512), dim3(512), 0, stream>>>(Qp, Kp, Vt, Oa);
    gemm_bt<bf16_t, float, float><<<dim3(8, 32), blk, 0, stream>>>(Oa, Wo, out, T_DIM, E_DIM, E_DIM, 1.0f);
  }
}